// Round 2
// baseline (347.792 us; speedup 1.0000x reference)
//
#include <hip/hip_runtime.h>
#include <math.h>

#define BB 128
#define PP 8732
#define CC 21
#define NNO 16
#define THRESH 0.5f
#define PCHUNKS 35   // ceil(8732/256)

__device__ __forceinline__ float sl1(float d) {
    float a = fabsf(d);
    return (a < 1.0f) ? 0.5f * a * a : a - 0.5f;
}

__device__ __forceinline__ float iou(float4 t, float at, float px0, float py0,
                                     float px1, float py1, float ap) {
    float ix0 = fmaxf(t.x, px0);
    float iy0 = fmaxf(t.y, py0);
    float ix1 = fminf(t.z, px1);
    float iy1 = fminf(t.w, py1);
    float iw = fmaxf(ix1 - ix0, 0.0f);
    float ih = fmaxf(iy1 - iy0, 0.0f);
    float inter = iw * ih;
    return inter / (at + ap - inter);
}

// ---------------- Kernel 1: per-(batch,truth) best prior ----------------
// grid (B, NNO), 256 threads: block argmax over all priors, first-index tie-break.
__global__ __launch_bounds__(256) void k_bestprior(
    const float4* __restrict__ priors,
    const float4* __restrict__ truths,
    int* __restrict__ bpi)               // [B*NNO]
{
    __shared__ float s_rv[4];
    __shared__ int   s_ri[4];
    const int b = blockIdx.x, j = blockIdx.y, tid = threadIdx.x;
    float4 t = truths[b * NNO + j];
    float at = (t.z - t.x) * (t.w - t.y);

    float bv = -1.0f; int bp = 0;
    for (int p = tid; p < PP; p += 256) {
        float4 pr = priors[p];
        float px0 = pr.x - pr.z * 0.5f, py0 = pr.y - pr.w * 0.5f;
        float px1 = pr.x + pr.z * 0.5f, py1 = pr.y + pr.w * 0.5f;
        float ap  = (px1 - px0) * (py1 - py0);
        float ov  = iou(t, at, px0, py0, px1, py1, ap);
        if (ov > bv) { bv = ov; bp = p; }        // ascending p -> keeps first max
    }
    const int lane = tid & 63, wv = tid >> 6;
#pragma unroll
    for (int off = 32; off >= 1; off >>= 1) {
        float ov = __shfl_down(bv, off);
        int   op = __shfl_down(bp, off);
        if (ov > bv || (ov == bv && op < bp)) { bv = ov; bp = op; }
    }
    if (lane == 0) { s_rv[wv] = bv; s_ri[wv] = bp; }
    __syncthreads();
    if (tid == 0) {
        for (int w = 1; w < 4; w++)
            if (s_rv[w] > bv || (s_rv[w] == bv && s_ri[w] < bp)) { bv = s_rv[w]; bp = s_ri[w]; }
        bpi[b * NNO + j] = bp;
    }
}

// ---------------- Kernel 2: assignment + conf targets + loc loss ----------------
// grid (B, PCHUNKS), 256 threads: one thread per prior.
__global__ __launch_bounds__(256) void k_assign(
    const float4* __restrict__ loc_data,
    const float4* __restrict__ priors,
    const float4* __restrict__ truths,
    const int*    __restrict__ labels,
    const int*    __restrict__ bpi,
    unsigned char* __restrict__ conf_t,
    int*   __restrict__ num_pos,
    float* __restrict__ loss_l_acc,
    int*   __restrict__ total_pos)
{
    __shared__ float4 s_t[NNO];
    __shared__ float  s_at[NNO];
    __shared__ int    s_lab[NNO];
    __shared__ int    s_bpi[NNO];
    __shared__ float  s_red[4];
    __shared__ int    s_redi[4];

    const int b = blockIdx.x, tid = threadIdx.x;
    const int p = blockIdx.y * 256 + tid;

    if (tid < NNO) {
        float4 t = truths[b * NNO + tid];
        s_t[tid]   = t;
        s_at[tid]  = (t.z - t.x) * (t.w - t.y);
        s_lab[tid] = labels[b * NNO + tid];
        s_bpi[tid] = bpi[b * NNO + tid];
    }
    __syncthreads();

    float lsum = 0.0f;
    int   np   = 0;
    if (p < PP) {
        float4 pr = priors[p];
        float px0 = pr.x - pr.z * 0.5f, py0 = pr.y - pr.w * 0.5f;
        float px1 = pr.x + pr.z * 0.5f, py1 = pr.y + pr.w * 0.5f;
        float ap  = (px1 - px0) * (py1 - py0);

        float bov = -1.0f; int bidx = 0;
#pragma unroll
        for (int j = 0; j < NNO; j++) {
            float ov = iou(s_t[j], s_at[j], px0, py0, px1, py1, ap);
            if (ov > bov) { bov = ov; bidx = j; }   // first-index argmax over truths
        }
        int forced = -1;
#pragma unroll
        for (int j = 0; j < NNO; j++) if (s_bpi[j] == p) forced = j;  // last-wins == scatter-max j
        if (forced >= 0) { bidx = forced; bov = 2.0f; }

        int lab = (bov < THRESH) ? 0 : s_lab[bidx];
        conf_t[(size_t)b * PP + p] = (unsigned char)lab;
        if (lab > 0) {
            np = 1;
            float4 t = s_t[bidx];
            float g0 = ((t.x + t.z) * 0.5f - pr.x) / (0.1f * pr.z);
            float g1 = ((t.y + t.w) * 0.5f - pr.y) / (0.1f * pr.w);
            float g2 = logf((t.z - t.x) / pr.z) / 0.2f;
            float g3 = logf((t.w - t.y) / pr.w) / 0.2f;
            float4 ld = loc_data[(size_t)b * PP + p];
            lsum = sl1(ld.x - g0) + sl1(ld.y - g1) + sl1(ld.z - g2) + sl1(ld.w - g3);
        }
    }
#pragma unroll
    for (int off = 32; off >= 1; off >>= 1) {
        lsum += __shfl_down(lsum, off);
        np   += __shfl_down(np, off);
    }
    const int lane = tid & 63, wv = tid >> 6;
    if (lane == 0) { s_red[wv] = lsum; s_redi[wv] = np; }
    __syncthreads();
    if (tid == 0) {
        float L = s_red[0] + s_red[1] + s_red[2] + s_red[3];
        int   N = s_redi[0] + s_redi[1] + s_redi[2] + s_redi[3];
        if (N) { atomicAdd(&num_pos[b], N); atomicAdd(total_pos, N); }
        if (L != 0.0f) atomicAdd(loss_l_acc, L);
    }
}

// ---------------- Kernel 3: per-row LSE, mining scores, positive CE ----------------
__global__ __launch_bounds__(256) void k_conf(
    const float* __restrict__ conf_data,
    const unsigned char* __restrict__ conf_t,
    float* __restrict__ loss_c,
    float* __restrict__ loss_c_acc)
{
    __shared__ float s_x[256 * CC];
    __shared__ float s_red[4];
    const int r0  = blockIdx.x * 256;
    const int tid = threadIdx.x;

    // 256*21 floats = 1344 float4s, 16B-aligned (r0*21*4 % 16 == 0)
    const float4* src4 = (const float4*)(conf_data + (size_t)r0 * CC);
    float4* dst4 = (float4*)s_x;
    for (int i = tid; i < (256 * CC) / 4; i += 256) dst4[i] = src4[i];
    __syncthreads();

    const float* x = s_x + tid * CC;
    float m = x[0];
#pragma unroll
    for (int c = 1; c < CC; c++) m = fmaxf(m, x[c]);
    float s = 0.0f;
#pragma unroll
    for (int c = 0; c < CC; c++) s += expf(x[c] - m);
    float lse = logf(s) + m;

    int ct = (int)conf_t[r0 + tid];
    float lc    = (ct > 0) ? 0.0f : (lse - x[0]);
    float posce = (ct > 0) ? (lse - x[ct]) : 0.0f;
    loss_c[r0 + tid] = lc;

#pragma unroll
    for (int off = 32; off >= 1; off >>= 1) posce += __shfl_down(posce, off);
    const int lane = tid & 63, wv = tid >> 6;
    if (lane == 0) s_red[wv] = posce;
    __syncthreads();
    if (tid == 0) {
        float v = s_red[0] + s_red[1] + s_red[2] + s_red[3];
        if (v != 0.0f) atomicAdd(loss_c_acc, v);
    }
}

// ---------------- Kernel 4: hard-negative mining (radix select, parallel scan) ----------------
#define MT 512
__global__ __launch_bounds__(MT) void k_mine(
    const float* __restrict__ loss_c,
    const int*   __restrict__ num_pos,
    float* __restrict__ loss_c_acc)
{
    __shared__ unsigned s_v[PP];        // float bits (all values >= 0: int order == float order)
    __shared__ int      s_S[257];       // suffix sums
    __shared__ int      s_cnt[8];
    __shared__ unsigned s_pref;
    __shared__ int      s_kp;
    __shared__ float    s_red[8];
    __shared__ int      s_redi[8];

    const int b   = blockIdx.x;
    const int tid = threadIdx.x;
    const int lane = tid & 63, wv = tid >> 6;

    const float* src = loss_c + (size_t)b * PP;
    for (int i = tid; i < PP; i += MT) s_v[i] = __float_as_uint(src[i]);
    int k = num_pos[b] * 3;
    if (k > PP - 1) k = PP - 1;
    __syncthreads();
    if (k <= 0) return;   // uniform across block

    unsigned prefix = 0, mask = 0;
    int kp = k;
    for (int shift = 24; shift >= 0; shift -= 8) {
        if (tid < 257) s_S[tid] = 0;
        __syncthreads();
        for (int i = tid; i < PP; i += MT) {
            unsigned u = s_v[i];
            if ((u & mask) == prefix) atomicAdd(&s_S[(u >> shift) & 255], 1);
        }
        __syncthreads();
        // parallel suffix sum over 256 bins (s_S[256] stays 0)
#pragma unroll
        for (int step = 1; step < 256; step <<= 1) {
            int v = 0;
            if (tid < 256) { v = s_S[tid]; if (tid + step < 256) v += s_S[tid + step]; }
            __syncthreads();
            if (tid < 256) s_S[tid] = v;
            __syncthreads();
        }
        // selected bin = max t with S[t] >= kp  == (count of such t) - 1 (S non-increasing)
        unsigned long long bal = __ballot(tid < 256 && s_S[tid] >= kp);
        if (lane == 0) s_cnt[wv] = __popcll(bal);
        __syncthreads();
        if (tid == 0) {
            int bin = (s_cnt[0] + s_cnt[1] + s_cnt[2] + s_cnt[3]) - 1;
            s_pref = prefix | ((unsigned)bin << shift);
            s_kp   = kp - s_S[bin + 1];
        }
        __syncthreads();
        prefix = s_pref;
        kp     = s_kp;
        mask  |= (0xFFu << shift);
        __syncthreads();
    }

    const float T = __uint_as_float(prefix);   // k-th largest value
    float sum = 0.0f; int cnt = 0;
    for (int i = tid; i < PP; i += MT) {
        unsigned u = s_v[i];
        if (u > prefix) { sum += __uint_as_float(u); cnt++; }
    }
#pragma unroll
    for (int off = 32; off >= 1; off >>= 1) {
        sum += __shfl_down(sum, off);
        cnt += __shfl_down(cnt, off);
    }
    if (lane == 0) { s_red[wv] = sum; s_redi[wv] = cnt; }
    __syncthreads();
    if (tid == 0) {
        float S = 0.0f; int G = 0;
        for (int w = 0; w < MT / 64; w++) { S += s_red[w]; G += s_redi[w]; }
        atomicAdd(loss_c_acc, S + (float)(k - G) * T);   // exact tie handling at the cutoff
    }
}

// ---------------- Kernel 5: finalize ----------------
__global__ void k_final(const float* __restrict__ acc, const int* __restrict__ total_pos,
                        float* __restrict__ out)
{
    float N = (float)total_pos[0];
    if (N < 1.0f) N = 1.0f;
    out[0] = acc[0] / N;
    out[1] = acc[1] / N;
}

extern "C" void kernel_launch(void* const* d_in, const int* in_sizes, int n_in,
                              void* d_out, int out_size, void* d_ws, size_t ws_size,
                              hipStream_t stream)
{
    const float4* loc    = (const float4*)d_in[0];
    const float*  conf   = (const float*)d_in[1];
    const float4* priors = (const float4*)d_in[2];
    const float4* truths = (const float4*)d_in[3];
    const int*    labels = (const int*)d_in[4];
    float* out = (float*)d_out;

    char* ws = (char*)d_ws;
    // layout: [0..7] float acc{loss_l, loss_c}; [8..11] int total_pos;
    //         [64..575] int num_pos[B]; [1024..9215] int bpi[B*NNO];
    //         [9216..] u8 conf_t[B*P]; then float loss_c[B*P]
    float*         acc       = (float*)ws;
    int*           total_pos = (int*)(ws + 8);
    int*           num_pos   = (int*)(ws + 64);
    int*           bpi       = (int*)(ws + 1024);
    unsigned char* conf_t    = (unsigned char*)(ws + 9216);
    float*         loss_c    = (float*)(ws + 9216 + (size_t)BB * PP);

    hipMemsetAsync(d_ws, 0, 1024, stream);   // acc, total_pos, num_pos
    k_bestprior<<<dim3(BB, NNO), 256, 0, stream>>>(priors, truths, bpi);
    k_assign<<<dim3(BB, PCHUNKS), 256, 0, stream>>>(loc, priors, truths, labels, bpi,
                                                    conf_t, num_pos, acc, total_pos);
    k_conf<<<(BB * PP) / 256, 256, 0, stream>>>(conf, conf_t, loss_c, acc + 1);
    k_mine<<<BB, MT, 0, stream>>>(loss_c, num_pos, acc + 1);
    k_final<<<1, 1, 0, stream>>>(acc, total_pos, out);
}

// Round 3
// 231.500 us; speedup vs baseline: 1.5023x; 1.5023x over previous
//
#include <hip/hip_runtime.h>
#include <math.h>

#define BB 128
#define PP 8732
#define CC 21
#define NNO 16
#define THRESH 0.5f
#define VP 4                 // priors per thread in k_assign
#define ACHUNK (256 * VP)    // 1024 priors per k_assign block
#define ACH 9                // ceil(8732/1024)
#define NSLOT 64

__device__ __forceinline__ float sl1(float d) {
    float a = fabsf(d);
    return (a < 1.0f) ? 0.5f * a * a : a - 0.5f;
}

__device__ __forceinline__ float iou(float4 t, float at, float px0, float py0,
                                     float px1, float py1, float ap) {
    float ix0 = fmaxf(t.x, px0);
    float iy0 = fmaxf(t.y, py0);
    float ix1 = fminf(t.z, px1);
    float iy1 = fminf(t.w, py1);
    float iw = fmaxf(ix1 - ix0, 0.0f);
    float ih = fmaxf(iy1 - iy0, 0.0f);
    float inter = iw * ih;
    return inter / (at + ap - inter);
}

// ---------------- Kernel 1: per-(batch,truth) best prior ----------------
__global__ __launch_bounds__(256) void k_bestprior(
    const float4* __restrict__ priors,
    const float4* __restrict__ truths,
    int* __restrict__ bpi)               // [B*NNO]
{
    __shared__ float s_rv[4];
    __shared__ int   s_ri[4];
    const int b = blockIdx.x, j = blockIdx.y, tid = threadIdx.x;
    float4 t = truths[b * NNO + j];
    float at = (t.z - t.x) * (t.w - t.y);

    float bv = -1.0f; int bp = 0;
    for (int p = tid; p < PP; p += 256) {
        float4 pr = priors[p];
        float px0 = pr.x - pr.z * 0.5f, py0 = pr.y - pr.w * 0.5f;
        float px1 = pr.x + pr.z * 0.5f, py1 = pr.y + pr.w * 0.5f;
        float ap  = (px1 - px0) * (py1 - py0);
        float ov  = iou(t, at, px0, py0, px1, py1, ap);
        if (ov > bv) { bv = ov; bp = p; }        // ascending p -> keeps first max
    }
    const int lane = tid & 63, wv = tid >> 6;
#pragma unroll
    for (int off = 32; off >= 1; off >>= 1) {
        float ov = __shfl_down(bv, off);
        int   op = __shfl_down(bp, off);
        if (ov > bv || (ov == bv && op < bp)) { bv = ov; bp = op; }
    }
    if (lane == 0) { s_rv[wv] = bv; s_ri[wv] = bp; }
    __syncthreads();
    if (tid == 0) {
        for (int w = 1; w < 4; w++)
            if (s_rv[w] > bv || (s_rv[w] == bv && s_ri[w] < bp)) { bv = s_rv[w]; bp = s_ri[w]; }
        bpi[b * NNO + j] = bp;
    }
}

// ---------------- Kernel 2: assignment + conf targets + loc loss ----------------
// grid (B, ACH), 256 threads, VP priors per thread.
__global__ __launch_bounds__(256) void k_assign(
    const float4* __restrict__ loc_data,
    const float4* __restrict__ priors,
    const float4* __restrict__ truths,
    const int*    __restrict__ labels,
    const int*    __restrict__ bpi,
    uchar4* __restrict__ conf_t,         // [B*P/4]
    int*   __restrict__ num_pos,         // [B]
    float* __restrict__ slotsL)          // [NSLOT]
{
    __shared__ float4 s_t[NNO];
    __shared__ float  s_at[NNO];
    __shared__ int    s_lab[NNO];
    __shared__ int    s_bpi[NNO];
    __shared__ float  s_red[4];
    __shared__ int    s_redi[4];

    const int b = blockIdx.x, tid = threadIdx.x;
    const int p0 = blockIdx.y * ACHUNK + tid * VP;

    if (tid < NNO) {
        float4 t = truths[b * NNO + tid];
        s_t[tid]   = t;
        s_at[tid]  = (t.z - t.x) * (t.w - t.y);
        s_lab[tid] = labels[b * NNO + tid];
        s_bpi[tid] = bpi[b * NNO + tid];
    }
    __syncthreads();

    float lsum = 0.0f;
    int   np   = 0;
    if (p0 < PP) {                       // PP % VP == 0, so whole quad is in-bounds
        uchar4 ct4;
        unsigned char* ctb = (unsigned char*)&ct4;
#pragma unroll
        for (int q = 0; q < VP; q++) {
            const int p = p0 + q;
            float4 pr = priors[p];
            float px0 = pr.x - pr.z * 0.5f, py0 = pr.y - pr.w * 0.5f;
            float px1 = pr.x + pr.z * 0.5f, py1 = pr.y + pr.w * 0.5f;
            float ap  = (px1 - px0) * (py1 - py0);

            float bov = -1.0f; int bidx = 0;
#pragma unroll
            for (int j = 0; j < NNO; j++) {
                float ov = iou(s_t[j], s_at[j], px0, py0, px1, py1, ap);
                if (ov > bov) { bov = ov; bidx = j; }   // first-index argmax over truths
            }
            int forced = -1;
#pragma unroll
            for (int j = 0; j < NNO; j++) if (s_bpi[j] == p) forced = j;  // last-wins == scatter-max j
            if (forced >= 0) { bidx = forced; bov = 2.0f; }

            int lab = (bov < THRESH) ? 0 : s_lab[bidx];
            ctb[q] = (unsigned char)lab;
            if (lab > 0) {
                np++;
                float4 t = s_t[bidx];
                float g0 = ((t.x + t.z) * 0.5f - pr.x) / (0.1f * pr.z);
                float g1 = ((t.y + t.w) * 0.5f - pr.y) / (0.1f * pr.w);
                float g2 = logf((t.z - t.x) / pr.z) / 0.2f;
                float g3 = logf((t.w - t.y) / pr.w) / 0.2f;
                float4 ld = loc_data[(size_t)b * PP + p];
                lsum += sl1(ld.x - g0) + sl1(ld.y - g1) + sl1(ld.z - g2) + sl1(ld.w - g3);
            }
        }
        conf_t[((size_t)b * PP + p0) >> 2] = ct4;
    }
#pragma unroll
    for (int off = 32; off >= 1; off >>= 1) {
        lsum += __shfl_down(lsum, off);
        np   += __shfl_down(np, off);
    }
    const int lane = tid & 63, wv = tid >> 6;
    if (lane == 0) { s_red[wv] = lsum; s_redi[wv] = np; }
    __syncthreads();
    if (tid == 0) {
        float L = s_red[0] + s_red[1] + s_red[2] + s_red[3];
        int   N = s_redi[0] + s_redi[1] + s_redi[2] + s_redi[3];
        if (N) atomicAdd(&num_pos[b], N);
        if (L != 0.0f) unsafeAtomicAdd(&slotsL[(b * ACH + blockIdx.y) & (NSLOT - 1)], L);
    }
}

// ---------------- Kernel 3: per-row LSE, mining scores, positive CE ----------------
__global__ __launch_bounds__(256) void k_conf(
    const float* __restrict__ conf_data,
    const unsigned char* __restrict__ conf_t,
    float* __restrict__ loss_c,
    float* __restrict__ slotsC)
{
    __shared__ float s_x[256 * CC];
    __shared__ float s_red[4];
    const int r0  = blockIdx.x * 256;
    const int tid = threadIdx.x;

    const float4* src4 = (const float4*)(conf_data + (size_t)r0 * CC);
    float4* dst4 = (float4*)s_x;
    for (int i = tid; i < (256 * CC) / 4; i += 256) dst4[i] = src4[i];
    __syncthreads();

    const float* x = s_x + tid * CC;
    float m = x[0];
#pragma unroll
    for (int c = 1; c < CC; c++) m = fmaxf(m, x[c]);
    float s = 0.0f;
#pragma unroll
    for (int c = 0; c < CC; c++) s += expf(x[c] - m);
    float lse = logf(s) + m;

    int ct = (int)conf_t[r0 + tid];
    float lc    = (ct > 0) ? 0.0f : (lse - x[0]);
    float posce = (ct > 0) ? (lse - x[ct]) : 0.0f;
    loss_c[r0 + tid] = lc;

#pragma unroll
    for (int off = 32; off >= 1; off >>= 1) posce += __shfl_down(posce, off);
    const int lane = tid & 63, wv = tid >> 6;
    if (lane == 0) s_red[wv] = posce;
    __syncthreads();
    if (tid == 0) {
        float v = s_red[0] + s_red[1] + s_red[2] + s_red[3];
        if (v != 0.0f) unsafeAtomicAdd(&slotsC[blockIdx.x & (NSLOT - 1)], v);
    }
}

// ---------------- Kernel 4: hard-negative mining (radix select) ----------------
#define MT 1024
#define NW (MT / 64)
__global__ __launch_bounds__(MT) void k_mine(
    const float* __restrict__ loss_c,
    const int*   __restrict__ num_pos,
    float* __restrict__ slotsC)
{
    __shared__ unsigned s_v[PP];        // float bits; all >= 0 so int order == float order
    __shared__ int      s_h[NW][256];   // per-wave histograms
    __shared__ unsigned s_pref;
    __shared__ int      s_kp;
    __shared__ float    s_red[NW];
    __shared__ int      s_redi[NW];

    const int b    = blockIdx.x;
    const int tid  = threadIdx.x;
    const int lane = tid & 63, wv = tid >> 6;

    const float* src = loss_c + (size_t)b * PP;
    for (int i = tid; i < PP; i += MT) s_v[i] = __float_as_uint(src[i]);
    int k = num_pos[b] * 3;
    if (k > PP - 1) k = PP - 1;
    __syncthreads();
    if (k <= 0) return;   // uniform across block

    unsigned prefix = 0, mask = 0;
    int kp = k;
    for (int shift = 24; shift >= 0; shift -= 8) {
        for (int i = tid; i < NW * 256; i += MT) ((int*)s_h)[i] = 0;
        __syncthreads();
        for (int i = tid; i < PP; i += MT) {
            unsigned u = s_v[i];
            if ((u & mask) == prefix) atomicAdd(&s_h[wv][(u >> shift) & 255], 1);
        }
        __syncthreads();
        if (wv == 0) {   // register-only suffix scan + select, no further barriers
            const int base = lane * 4;
            int h0 = 0, h1 = 0, h2 = 0, h3 = 0;
            for (int w = 0; w < NW; w++) {
                h0 += s_h[w][base]; h1 += s_h[w][base + 1];
                h2 += s_h[w][base + 2]; h3 += s_h[w][base + 3];
            }
            int sf3 = h3, sf2 = h2 + sf3, sf1 = h1 + sf2, sf0 = h0 + sf1;
            int g = sf0;
#pragma unroll
            for (int off = 1; off < 64; off <<= 1) {
                int t = __shfl_down(g, off);
                if (lane + off < 64) g += t;
            }
            int above = g - sf0;                  // sum over lanes > this lane
            int S0 = above + sf0, S1 = above + sf1, S2 = above + sf2, S3 = above + sf3;
            int c = (S0 >= kp) + (S1 >= kp) + (S2 >= kp) + (S3 >= kp);
            int ct = c;
#pragma unroll
            for (int off = 1; off < 64; off <<= 1) {
                int t = __shfl_down(ct, off);
                if (lane + off < 64) ct += t;
            }
            int idx = __shfl(ct, 0);              // = bin + 1 (count of bins with S >= kp)
            int j = idx & 3, srcl = (idx >> 2) & 63;
            int Ssel = (j == 0) ? S0 : ((j == 1) ? S1 : ((j == 2) ? S2 : S3));
            int Snext = __shfl(Ssel, srcl);
            if (idx >= 256) Snext = 0;
            if (lane == 0) {
                s_pref = prefix | ((unsigned)(idx - 1) << shift);
                s_kp   = kp - Snext;
            }
        }
        __syncthreads();
        prefix = s_pref;
        kp     = s_kp;
        mask  |= (0xFFu << shift);
    }

    const float T = __uint_as_float(prefix);   // k-th largest value
    float sum = 0.0f; int cnt = 0;
    for (int i = tid; i < PP; i += MT) {
        unsigned u = s_v[i];
        if (u > prefix) { sum += __uint_as_float(u); cnt++; }
    }
#pragma unroll
    for (int off = 32; off >= 1; off >>= 1) {
        sum += __shfl_down(sum, off);
        cnt += __shfl_down(cnt, off);
    }
    if (lane == 0) { s_red[wv] = sum; s_redi[wv] = cnt; }
    __syncthreads();
    if (tid == 0) {
        float S = 0.0f; int G = 0;
        for (int w = 0; w < NW; w++) { S += s_red[w]; G += s_redi[w]; }
        unsafeAtomicAdd(&slotsC[b & (NSLOT - 1)], S + (float)(k - G) * T);  // exact ties at cutoff
    }
}

// ---------------- Kernel 5: finalize ----------------
__global__ __launch_bounds__(64) void k_final(
    const float* __restrict__ slotsL, const float* __restrict__ slotsC,
    const int* __restrict__ num_pos, float* __restrict__ out)
{
    const int lane = threadIdx.x;
    float L = slotsL[lane];
    float C = slotsC[lane];
    int   N = num_pos[lane] + num_pos[lane + 64];
#pragma unroll
    for (int off = 32; off >= 1; off >>= 1) {
        L += __shfl_down(L, off);
        C += __shfl_down(C, off);
        N += __shfl_down(N, off);
    }
    if (lane == 0) {
        float Nf = (float)N;
        if (Nf < 1.0f) Nf = 1.0f;
        out[0] = L / Nf;
        out[1] = C / Nf;
    }
}

extern "C" void kernel_launch(void* const* d_in, const int* in_sizes, int n_in,
                              void* d_out, int out_size, void* d_ws, size_t ws_size,
                              hipStream_t stream)
{
    const float4* loc    = (const float4*)d_in[0];
    const float*  conf   = (const float*)d_in[1];
    const float4* priors = (const float4*)d_in[2];
    const float4* truths = (const float4*)d_in[3];
    const int*    labels = (const int*)d_in[4];
    float* out = (float*)d_out;

    char* ws = (char*)d_ws;
    // layout: [0..255] float slotsL[64]; [256..511] float slotsC[64];
    //         [512..1023] int num_pos[128]; [1024..9215] int bpi[B*NNO];
    //         [9216..] u8 conf_t[B*P]; then float loss_c[B*P]
    float* slotsL  = (float*)ws;
    float* slotsC  = (float*)(ws + 256);
    int*   num_pos = (int*)(ws + 512);
    int*   bpi     = (int*)(ws + 1024);
    unsigned char* conf_t = (unsigned char*)(ws + 9216);
    float* loss_c  = (float*)(ws + 9216 + (size_t)BB * PP);

    hipMemsetAsync(d_ws, 0, 1024, stream);   // slots + num_pos
    k_bestprior<<<dim3(BB, NNO), 256, 0, stream>>>(priors, truths, bpi);
    k_assign<<<dim3(BB, ACH), 256, 0, stream>>>(loc, priors, truths, labels, bpi,
                                                (uchar4*)conf_t, num_pos, slotsL);
    k_conf<<<(BB * PP) / 256, 256, 0, stream>>>(conf, conf_t, loss_c, slotsC);
    k_mine<<<BB, MT, 0, stream>>>(loss_c, num_pos, slotsC);
    k_final<<<1, 64, 0, stream>>>(slotsL, slotsC, num_pos, out);
}

// Round 4
// 212.169 us; speedup vs baseline: 1.6392x; 1.0911x over previous
//
#include <hip/hip_runtime.h>
#include <math.h>

#define BB 128
#define PP 8732
#define CC 21
#define NNO 16
#define THRESH 0.5f
#define FCH 35               // ceil(8732/256)
#define NSLOT 64

__device__ __forceinline__ float sl1(float d) {
    float a = fabsf(d);
    return (a < 1.0f) ? 0.5f * a * a : a - 0.5f;
}

__device__ __forceinline__ float iou(float4 t, float at, float px0, float py0,
                                     float px1, float py1, float ap) {
    float ix0 = fmaxf(t.x, px0);
    float iy0 = fmaxf(t.y, py0);
    float ix1 = fminf(t.z, px1);
    float iy1 = fminf(t.w, py1);
    float iw = fmaxf(ix1 - ix0, 0.0f);
    float ih = fmaxf(iy1 - iy0, 0.0f);
    float inter = iw * ih;
    return inter / (at + ap - inter);
}

// ---------------- Kernel 1: per-(batch,truth) best prior + ws zero-init ----------------
__global__ __launch_bounds__(256) void k_bestprior(
    const float4* __restrict__ priors,
    const float4* __restrict__ truths,
    int* __restrict__ bpi,               // [B*NNO]
    uint4* __restrict__ zero_base)       // 1024 bytes: slotsL|slotsC|num_pos
{
    __shared__ float s_rv[4];
    __shared__ int   s_ri[4];
    const int b = blockIdx.x, j = blockIdx.y, tid = threadIdx.x;

    // fold the 1KB accumulator zeroing into one block (consumers are later dispatches)
    if (b == 0 && j == 0 && tid < 64) zero_base[tid] = make_uint4(0, 0, 0, 0);

    float4 t = truths[b * NNO + j];
    float at = (t.z - t.x) * (t.w - t.y);

    float bv = -1.0f; int bp = 0;
    for (int p = tid; p < PP; p += 256) {
        float4 pr = priors[p];
        float px0 = pr.x - pr.z * 0.5f, py0 = pr.y - pr.w * 0.5f;
        float px1 = pr.x + pr.z * 0.5f, py1 = pr.y + pr.w * 0.5f;
        float ap  = (px1 - px0) * (py1 - py0);
        float ov  = iou(t, at, px0, py0, px1, py1, ap);
        if (ov > bv) { bv = ov; bp = p; }        // ascending p -> keeps first max
    }
    const int lane = tid & 63, wv = tid >> 6;
#pragma unroll
    for (int off = 32; off >= 1; off >>= 1) {
        float ov = __shfl_down(bv, off);
        int   op = __shfl_down(bp, off);
        if (ov > bv || (ov == bv && op < bp)) { bv = ov; bp = op; }
    }
    if (lane == 0) { s_rv[wv] = bv; s_ri[wv] = bp; }
    __syncthreads();
    if (tid == 0) {
        for (int w = 1; w < 4; w++)
            if (s_rv[w] > bv || (s_rv[w] == bv && s_ri[w] < bp)) { bv = s_rv[w]; bp = s_ri[w]; }
        bpi[b * NNO + j] = bp;
    }
}

// ---------------- Kernel 2: fused matching + loc loss + LSE + mining scores ----------------
// grid (B, FCH), 256 threads: one thread per (batch, prior) row.
__global__ __launch_bounds__(256) void k_fused(
    const float4* __restrict__ loc_data,
    const float*  __restrict__ conf_data,
    const float4* __restrict__ priors,
    const float4* __restrict__ truths,
    const int*    __restrict__ labels,
    const int*    __restrict__ bpi,
    float* __restrict__ loss_c,          // [B*P]
    int*   __restrict__ num_pos,         // [B]
    float* __restrict__ slotsL,          // [NSLOT]
    float* __restrict__ slotsC)          // [NSLOT]
{
    __shared__ float  s_x[256 * CC];
    __shared__ float4 s_t[NNO];
    __shared__ float  s_at[NNO];
    __shared__ int    s_lab[NNO];
    __shared__ int    s_bpi[NNO];
    __shared__ float  s_redL[4], s_redC[4];
    __shared__ int    s_redi[4];

    const int b   = blockIdx.x, tid = threadIdx.x;
    const int r0  = blockIdx.y * 256;
    const int p   = r0 + tid;
    const int nrow = (PP - r0 < 256) ? (PP - r0) : 256;

    if (tid < NNO) {
        float4 t = truths[b * NNO + tid];
        s_t[tid]   = t;
        s_at[tid]  = (t.z - t.x) * (t.w - t.y);
        s_lab[tid] = labels[b * NNO + tid];
        s_bpi[tid] = bpi[b * NNO + tid];
    }
    // stage this block's conf rows; (b*PP + r0)*CC is divisible by 4 (PP%4==0, r0%4==0)
    const float4* src4 = (const float4*)(conf_data + ((size_t)b * PP + r0) * CC);
    const int nf4 = nrow * CC / 4;       // nrow*CC always divisible by 4 here
    float4* dst4 = (float4*)s_x;
    for (int i = tid; i < nf4; i += 256) dst4[i] = src4[i];
    __syncthreads();

    float lsum = 0.0f, posce = 0.0f;
    int   np   = 0;
    if (p < PP) {
        float4 pr = priors[p];
        float px0 = pr.x - pr.z * 0.5f, py0 = pr.y - pr.w * 0.5f;
        float px1 = pr.x + pr.z * 0.5f, py1 = pr.y + pr.w * 0.5f;
        float ap  = (px1 - px0) * (py1 - py0);

        float bov = -1.0f; int bidx = 0;
#pragma unroll
        for (int j = 0; j < NNO; j++) {
            float ov = iou(s_t[j], s_at[j], px0, py0, px1, py1, ap);
            if (ov > bov) { bov = ov; bidx = j; }   // first-index argmax over truths
        }
        int forced = -1;
#pragma unroll
        for (int j = 0; j < NNO; j++) if (s_bpi[j] == p) forced = j;  // last-wins == scatter-max j
        if (forced >= 0) { bidx = forced; bov = 2.0f; }
        int lab = (bov < THRESH) ? 0 : s_lab[bidx];

        const float* x = s_x + tid * CC;
        float m = x[0];
#pragma unroll
        for (int c = 1; c < CC; c++) m = fmaxf(m, x[c]);
        float s = 0.0f;
#pragma unroll
        for (int c = 0; c < CC; c++) s += expf(x[c] - m);
        float lse = logf(s) + m;

        loss_c[(size_t)b * PP + p] = (lab > 0) ? 0.0f : (lse - x[0]);
        if (lab > 0) {
            np = 1;
            posce = lse - x[lab];
            float4 t = s_t[bidx];
            float g0 = ((t.x + t.z) * 0.5f - pr.x) / (0.1f * pr.z);
            float g1 = ((t.y + t.w) * 0.5f - pr.y) / (0.1f * pr.w);
            float g2 = logf((t.z - t.x) / pr.z) / 0.2f;
            float g3 = logf((t.w - t.y) / pr.w) / 0.2f;
            float4 ld = loc_data[(size_t)b * PP + p];
            lsum = sl1(ld.x - g0) + sl1(ld.y - g1) + sl1(ld.z - g2) + sl1(ld.w - g3);
        }
    }
#pragma unroll
    for (int off = 32; off >= 1; off >>= 1) {
        lsum  += __shfl_down(lsum, off);
        posce += __shfl_down(posce, off);
        np    += __shfl_down(np, off);
    }
    const int lane = tid & 63, wv = tid >> 6;
    if (lane == 0) { s_redL[wv] = lsum; s_redC[wv] = posce; s_redi[wv] = np; }
    __syncthreads();
    if (tid == 0) {
        float L = s_redL[0] + s_redL[1] + s_redL[2] + s_redL[3];
        float C = s_redC[0] + s_redC[1] + s_redC[2] + s_redC[3];
        int   N = s_redi[0] + s_redi[1] + s_redi[2] + s_redi[3];
        if (N) {
            atomicAdd(&num_pos[b], N);
            unsafeAtomicAdd(&slotsL[(b * FCH + blockIdx.y) & (NSLOT - 1)], L);
            unsafeAtomicAdd(&slotsC[(b * FCH + blockIdx.y) & (NSLOT - 1)], C);
        }
    }
}

// ---------------- Kernel 3: hard-negative mining (radix select) ----------------
#define MT 1024
#define NW (MT / 64)
__global__ __launch_bounds__(MT) void k_mine(
    const float* __restrict__ loss_c,
    const int*   __restrict__ num_pos,
    float* __restrict__ slotsC)
{
    __shared__ unsigned s_v[PP];        // float bits; all >= 0 so int order == float order
    __shared__ int      s_h[NW][256];   // per-wave histograms
    __shared__ unsigned s_pref;
    __shared__ int      s_kp;
    __shared__ float    s_red[NW];
    __shared__ int      s_redi[NW];

    const int b    = blockIdx.x;
    const int tid  = threadIdx.x;
    const int lane = tid & 63, wv = tid >> 6;

    const float* src = loss_c + (size_t)b * PP;
    for (int i = tid; i < PP; i += MT) s_v[i] = __float_as_uint(src[i]);
    int k = num_pos[b] * 3;
    if (k > PP - 1) k = PP - 1;
    __syncthreads();
    if (k <= 0) return;   // uniform across block

    unsigned prefix = 0, mask = 0;
    int kp = k;
    for (int shift = 24; shift >= 0; shift -= 8) {
        for (int i = tid; i < NW * 256; i += MT) ((int*)s_h)[i] = 0;
        __syncthreads();
        for (int i = tid; i < PP; i += MT) {
            unsigned u = s_v[i];
            if ((u & mask) == prefix) atomicAdd(&s_h[wv][(u >> shift) & 255], 1);
        }
        __syncthreads();
        if (wv == 0) {   // register-only suffix scan + select
            const int base = lane * 4;
            int h0 = 0, h1 = 0, h2 = 0, h3 = 0;
            for (int w = 0; w < NW; w++) {
                h0 += s_h[w][base]; h1 += s_h[w][base + 1];
                h2 += s_h[w][base + 2]; h3 += s_h[w][base + 3];
            }
            int sf3 = h3, sf2 = h2 + sf3, sf1 = h1 + sf2, sf0 = h0 + sf1;
            int g = sf0;
#pragma unroll
            for (int off = 1; off < 64; off <<= 1) {
                int t = __shfl_down(g, off);
                if (lane + off < 64) g += t;
            }
            int above = g - sf0;                  // sum over lanes > this lane
            int S0 = above + sf0, S1 = above + sf1, S2 = above + sf2, S3 = above + sf3;
            int c = (S0 >= kp) + (S1 >= kp) + (S2 >= kp) + (S3 >= kp);
            int ct = c;
#pragma unroll
            for (int off = 1; off < 64; off <<= 1) {
                int t = __shfl_down(ct, off);
                if (lane + off < 64) ct += t;
            }
            int idx = __shfl(ct, 0);              // = bin + 1 (count of bins with S >= kp)
            int j = idx & 3, srcl = (idx >> 2) & 63;
            int Ssel = (j == 0) ? S0 : ((j == 1) ? S1 : ((j == 2) ? S2 : S3));
            int Snext = __shfl(Ssel, srcl);
            if (idx >= 256) Snext = 0;
            if (lane == 0) {
                s_pref = prefix | ((unsigned)(idx - 1) << shift);
                s_kp   = kp - Snext;
            }
        }
        __syncthreads();
        prefix = s_pref;
        kp     = s_kp;
        mask  |= (0xFFu << shift);
    }

    const float T = __uint_as_float(prefix);   // k-th largest value
    float sum = 0.0f; int cnt = 0;
    for (int i = tid; i < PP; i += MT) {
        unsigned u = s_v[i];
        if (u > prefix) { sum += __uint_as_float(u); cnt++; }
    }
#pragma unroll
    for (int off = 32; off >= 1; off >>= 1) {
        sum += __shfl_down(sum, off);
        cnt += __shfl_down(cnt, off);
    }
    if (lane == 0) { s_red[wv] = sum; s_redi[wv] = cnt; }
    __syncthreads();
    if (tid == 0) {
        float S = 0.0f; int G = 0;
        for (int w = 0; w < NW; w++) { S += s_red[w]; G += s_redi[w]; }
        unsafeAtomicAdd(&slotsC[b & (NSLOT - 1)], S + (float)(k - G) * T);  // exact ties at cutoff
    }
}

// ---------------- Kernel 4: finalize ----------------
__global__ __launch_bounds__(64) void k_final(
    const float* __restrict__ slotsL, const float* __restrict__ slotsC,
    const int* __restrict__ num_pos, float* __restrict__ out)
{
    const int lane = threadIdx.x;
    float L = slotsL[lane];
    float C = slotsC[lane];
    int   N = num_pos[lane] + num_pos[lane + 64];
#pragma unroll
    for (int off = 32; off >= 1; off >>= 1) {
        L += __shfl_down(L, off);
        C += __shfl_down(C, off);
        N += __shfl_down(N, off);
    }
    if (lane == 0) {
        float Nf = (float)N;
        if (Nf < 1.0f) Nf = 1.0f;
        out[0] = L / Nf;
        out[1] = C / Nf;
    }
}

extern "C" void kernel_launch(void* const* d_in, const int* in_sizes, int n_in,
                              void* d_out, int out_size, void* d_ws, size_t ws_size,
                              hipStream_t stream)
{
    const float4* loc    = (const float4*)d_in[0];
    const float*  conf   = (const float*)d_in[1];
    const float4* priors = (const float4*)d_in[2];
    const float4* truths = (const float4*)d_in[3];
    const int*    labels = (const int*)d_in[4];
    float* out = (float*)d_out;

    char* ws = (char*)d_ws;
    // layout: [0..255] float slotsL[64]; [256..511] float slotsC[64];
    //         [512..1023] int num_pos[128]; [1024..9215] int bpi[B*NNO];
    //         [9216..] float loss_c[B*P]
    float* slotsL  = (float*)ws;
    float* slotsC  = (float*)(ws + 256);
    int*   num_pos = (int*)(ws + 512);
    int*   bpi     = (int*)(ws + 1024);
    float* loss_c  = (float*)(ws + 9216);

    k_bestprior<<<dim3(BB, NNO), 256, 0, stream>>>(priors, truths, bpi, (uint4*)ws);
    k_fused<<<dim3(BB, FCH), 256, 0, stream>>>(loc, conf, priors, truths, labels, bpi,
                                               loss_c, num_pos, slotsL, slotsC);
    k_mine<<<BB, MT, 0, stream>>>(loss_c, num_pos, slotsC);
    k_final<<<1, 64, 0, stream>>>(slotsL, slotsC, num_pos, out);
}